// Round 4
// baseline (493.514 us; speedup 1.0000x reference)
//
#include <hip/hip_runtime.h>
#include <cstdint>
#include <cstddef>

typedef unsigned short ushort_t;
typedef __attribute__((ext_vector_type(4))) float f32x4;
typedef __attribute__((ext_vector_type(8))) short s16x8;

#define PI_4F 0.78539816339744830962f

// round-to-nearest-even fp32 -> bf16
__device__ inline ushort_t f2bf(float f) {
  unsigned int u = __float_as_uint(f);
  u = u + 0x7fffu + ((u >> 16) & 1u);
  return (ushort_t)(u >> 16);
}

__device__ inline void gload16(const ushort_t* g, ushort_t* l) {
  __builtin_amdgcn_global_load_lds(
      (const __attribute__((address_space(1))) unsigned int*)g,
      (__attribute__((address_space(3))) unsigned int*)l, 16, 0, 0);
}

// Device-scope grid barrier. SAFE ONLY because all 512 blocks are co-resident
// (LDS 72KB -> 2 blocks/CU, launch_bounds(512,4) -> VGPR<=128 -> 16 waves/CU).
__device__ inline void grid_barrier(unsigned int* bar, unsigned int target) {
  __threadfence();   // agent-scope release of this thread's writes (L2 WB)
  __syncthreads();   // whole block's fences done
  if (threadIdx.x == 0) {
    __hip_atomic_fetch_add(bar, 1u, __ATOMIC_ACQ_REL, __HIP_MEMORY_SCOPE_AGENT);
    while (__hip_atomic_load(bar, __ATOMIC_ACQUIRE, __HIP_MEMORY_SCOPE_AGENT) < target) {}
  }
  __syncthreads();
  __threadfence();   // acquire: invalidate L1 so we see other XCDs' data
}

// ---------------------------------------------------------------------------
// Megakernel: 512 blocks x 512 threads.
//   Phase 1: per-block rot (threads 0..3, in LDS) + wt slice + xpad transpose
//            slice + border slice.   [grid barrier]
//   Phase 2: implicit-GEMM conv, bf16 MFMA, 3-stage vmcnt pipeline.
// Block decode (used for BOTH phases so producer/consumer locality aligns):
//   xcd = id&7, j = id>>3, b = xcd*2 + (j>>5), ntile = j&31.
// Conv tile: 256 o x 128 hw, BK=32, 72 K-steps; 8 waves, wave tile 64x64,
// acc 4x4 of 16x16x32 MFMA. LDS 3 x (16KB A + 8KB B) = 72 KB.
// XOR swizzle (R2-verified): storage 16B chunk = cg ^ ((row>>1)&3).
// ---------------------------------------------------------------------------
__global__ __launch_bounds__(512, 4) void mega_kernel(
    const float* __restrict__ x, const float* __restrict__ thetas,
    const float* __restrict__ scales, const float* __restrict__ lambdas,
    const float* __restrict__ weight, float* __restrict__ out,
    unsigned int* __restrict__ bar, ushort_t* __restrict__ wt,
    ushort_t* __restrict__ xpad) {
  __shared__ __align__(16) ushort_t smem[3][12288];  // 3 stages x 24 KB

  const int id = blockIdx.x;
  const int xcd = id & 7;
  const int jj = id >> 3;
  const int b = xcd * 2 + (jj >> 5);
  const int ntile = jj & 31;
  const int t = threadIdx.x;

  // ======================= Phase 1a: rot -> LDS =======================
  float* ldsrot = (float*)&smem[0][0];  // [4][81]
  if (t < 324) ldsrot[t] = 0.0f;
  __syncthreads();
  if (t < 4) {
    const int gi = b * 4 + t;
    float th = thetas[gi], s = scales[gi], lam = lambdas[gi];
    float xv = cosf(th) * s, yv = sinf(th) * s;
    bool pos = (th >= 0.0f), big = (s >= 1.0f), m1 = (fabsf(th) <= PI_4F);
    float* R = ldsrot + t * 81;
    R[40] = lam;  // center
    if (pos) {
      float a = xv - yv, bb = xv * yv, cc = xv + yv;
      if (m1 && big) {
        R[0]=a*lam; R[1]=(1-a)*lam;
        R[10]=(1-yv)*lam; R[11]=yv*lam;
        R[20]=a*lam; R[23]=(1-a)*lam;
        R[27]=yv*lam; R[30]=(1-yv)*lam;
        R[50]=(1-yv)*lam; R[53]=yv*lam;
        R[57]=(1-a)*lam; R[60]=a*lam;
        R[69]=yv*lam; R[70]=(1-yv)*lam;
        R[79]=(1-a)*lam; R[80]=a*lam;
      } else if (m1) {
        float d = a * cc, e = a + cc;
        R[0]=d*lam; R[1]=(a-d)*lam; R[3]=(cc-d)*lam; R[4]=(1-e+d)*lam;
        R[10]=(xv-bb)*lam; R[11]=bb*lam; R[13]=(1-cc+bb)*lam; R[14]=(yv-bb)*lam;
        R[19]=(cc-d)*lam; R[20]=d*lam; R[22]=(1-e+d)*lam; R[23]=(a-d)*lam;
        R[27]=bb*lam; R[28]=(yv-bb)*lam; R[30]=(xv-bb)*lam; R[31]=(1-cc+bb)*lam;
        R[49]=(1-cc+bb)*lam; R[50]=(xv-bb)*lam; R[52]=(yv-bb)*lam; R[53]=bb*lam;
        R[57]=(a-d)*lam; R[58]=(1-e+d)*lam; R[60]=d*lam; R[61]=(cc-d)*lam;
        R[66]=(yv-bb)*lam; R[67]=(1-cc+bb)*lam; R[69]=bb*lam; R[70]=(xv-bb)*lam;
        R[76]=(1-e+d)*lam; R[77]=(cc-d)*lam; R[79]=(a-d)*lam; R[80]=d*lam;
      } else {
        R[0]=a*lam; R[1]=(1-a)*lam;
        R[10]=(xv-bb)*lam; R[11]=bb*lam; R[13]=(1-cc+bb)*lam; R[14]=(yv-bb)*lam;
        R[20]=a*lam; R[23]=(1-a)*lam;
        R[27]=bb*lam; R[28]=(yv-bb)*lam; R[30]=(xv-bb)*lam; R[31]=(1-cc+bb)*lam;
        R[49]=(1-cc+bb)*lam; R[50]=(xv-bb)*lam; R[52]=(yv-bb)*lam; R[53]=bb*lam;
        R[57]=(1-a)*lam; R[60]=a*lam;
        R[66]=(yv-bb)*lam; R[67]=(1-cc+bb)*lam; R[69]=bb*lam; R[70]=(xv-bb)*lam;
        R[79]=(1-a)*lam; R[80]=a*lam;
      }
    } else {
      float yp = -yv;
      float ap = xv - yp, bp = xv * yp, cp = xv + yp;
      if (m1 && big) {
        R[0]=cp*lam; R[3]=(1-cp)*lam;
        R[9]=yp*lam; R[10]=(1-yp)*lam;
        R[19]=(1-cp)*lam; R[20]=cp*lam;
        R[30]=(1-yp)*lam; R[33]=yp*lam;
        R[47]=yp*lam; R[50]=(1-yp)*lam;
        R[60]=cp*lam; R[61]=(1-cp)*lam;
        R[70]=(1-yp)*lam; R[71]=yp*lam;
        R[77]=(1-cp)*lam; R[80]=cp*lam;
      } else if (m1) {
        float dp = ap * cp, ep = ap + cp;
        R[0]=dp*lam; R[1]=(cp-dp)*lam; R[3]=(ap-dp)*lam; R[4]=(1-ep+dp)*lam;
        R[9]=bp*lam; R[10]=(xv-bp)*lam; R[12]=(yp-bp)*lam; R[13]=(1-cp+bp)*lam;
        R[19]=(ap-dp)*lam; R[20]=dp*lam; R[22]=(1-ep+dp)*lam; R[23]=(cp-dp)*lam;
        R[28]=(yp-bp)*lam; R[29]=bp*lam; R[31]=(1-cp+bp)*lam; R[32]=(xv-bp)*lam;
        R[48]=(xv-bp)*lam; R[49]=(1-cp+bp)*lam; R[51]=bp*lam; R[52]=(yp-bp)*lam;
        R[57]=(cp-dp)*lam; R[58]=(1-ep+dp)*lam; R[60]=dp*lam; R[61]=(ap-dp)*lam;
        R[67]=(1-cp+bp)*lam; R[68]=(yp-bp)*lam; R[70]=(xv-bp)*lam; R[71]=bp*lam;
        R[76]=(1-ep+dp)*lam; R[77]=(ap-dp)*lam; R[79]=(cp-dp)*lam; R[80]=dp*lam;
      } else {
        R[0]=cp*lam; R[3]=(1-cp)*lam;
        R[9]=bp*lam; R[10]=(xv-bp)*lam; R[12]=(yp-bp)*lam; R[13]=(1-cp+bp)*lam;
        R[19]=(1-cp)*lam; R[20]=cp*lam;
        R[30]=(xv-bp)*lam; R[31]=(1-cp+bp)*lam; R[33]=bp*lam; R[34]=(yp-bp)*lam;
        R[46]=(yp-bp)*lam; R[47]=bp*lam; R[49]=(1-cp+bp)*lam; R[50]=(xv-bp)*lam;
        R[60]=cp*lam; R[61]=(1-cp)*lam;
        R[67]=(1-cp+bp)*lam; R[68]=(yp-bp)*lam; R[70]=(xv-bp)*lam; R[71]=bp*lam;
        R[77]=(1-cp)*lam; R[80]=cp*lam;
      }
    }
  }
  __syncthreads();

  // ======================= Phase 1b: wt slice =======================
  // This block: batch b, o = ntile*8 + (t>>8)*4 + oo, c = t&255.
  {
    const int c = t & 255;
    const int o_base = ntile * 8 + (t >> 8) * 4;
    float acc[4][9];
#pragma unroll
    for (int oo = 0; oo < 4; ++oo)
#pragma unroll
      for (int i = 0; i < 9; ++i) acc[oo][i] = 0.0f;
#pragma unroll
    for (int n = 0; n < 4; ++n)
#pragma unroll
      for (int j2 = 0; j2 < 9; ++j2) {
        float wv4[4];
#pragma unroll
        for (int oo = 0; oo < 4; ++oo)
          wv4[oo] = weight[((size_t)((n * 256 + o_base + oo)) * 256 + c) * 9 + j2];
#pragma unroll
        for (int i = 0; i < 9; ++i) {
          float r = ldsrot[n * 81 + i * 9 + j2];  // broadcast LDS read
#pragma unroll
          for (int oo = 0; oo < 4; ++oo) acc[oo][i] = fmaf(r, wv4[oo], acc[oo][i]);
        }
      }
#pragma unroll
    for (int oo = 0; oo < 4; ++oo)
#pragma unroll
      for (int i = 0; i < 9; ++i)
        wt[((size_t)((b * 9 + i) * 256 + o_base + oo)) * 256 + c] = f2bf(acc[oo][i]);
  }

  // ======================= Phase 1c: transpose slice =======================
  // 8 tiles per block; tile = (st h-row 0..63, ct c-group 0..3); x->xpad bf16.
  {
    ushort_t(*tile)[72] = (ushort_t(*)[72]) & smem[0][0];  // 64 x 72 (16B-aligned rows)
#pragma unroll 1
    for (int k = 0; k < 8; ++k) {
      const int tu = ntile * 8 + k;
      const int st = tu >> 2, ct = tu & 3;
      const float* xb = x + ((size_t)(b * 256 + ct * 64)) * 4096 + st * 64;
      __syncthreads();  // prev tile fully read / rot reads done
#pragma unroll
      for (int kk = 0; kk < 8; ++kk) {
        int cL = (t >> 6) + 8 * kk;
        tile[t & 63][cL] = f2bf(xb[(size_t)cL * 4096 + (t & 63)]);
      }
      __syncthreads();
      const int w2 = t >> 3, c8 = (t & 7) * 8;
      uint4 v = *(const uint4*)&tile[w2][c8];
      *(uint4*)&xpad[((size_t)(b * 4356 + (st + 1) * 66 + (w2 + 1))) * 256 + ct * 64 + c8] = v;
    }
  }

  // ======================= Phase 1d: border slice =======================
  if (t < 288) {
    int p = ntile * 8 + (t >> 5);
    if (p < 260) {
      int h, w;
      if (p < 66) { h = 0; w = p; }
      else if (p < 132) { h = 65; w = p - 66; }
      else if (p < 196) { w = 0; h = p - 131; }
      else { w = 65; h = p - 195; }
      uint4 z4 = make_uint4(0u, 0u, 0u, 0u);
      *(uint4*)&xpad[((size_t)(b * 4356 + h * 66 + w)) * 256 + (t & 31) * 8] = z4;
    }
  }

  grid_barrier(bar, 512u);

  // ======================= Phase 2: conv =======================
  const int wave = t >> 6, lane = t & 63;
  const int wm = wave & 3, wn = wave >> 2;
  const int lr = lane & 15, lq = lane >> 4;
  const int h0 = ntile * 2;

  const ushort_t* wt_b = wt + (size_t)b * 589824;     // 9*256*256
  const ushort_t* xp_b = xpad + (size_t)b * 1115136;  // 4356*256

  const int lrow = t >> 2;                           // 0..127
  const int cg8 = (((t & 3) ^ ((t >> 3) & 3)) * 8);  // swizzled global 16B chunk
  const int rsw = (lr >> 1) & 3;
  const int aoff = (wm * 64 + lr) * 32 + ((lq ^ rsw) * 8);
  const int boff = (wn * 64 + lr) * 32 + ((lq ^ rsw) * 8);
  const int nrow2 = 2 * (lrow >> 6);  // xpad row-adjust for B n>=64

  f32x4 acc[4][4];
#pragma unroll
  for (int i = 0; i < 4; ++i)
#pragma unroll
    for (int j2 = 0; j2 < 4; ++j2) acc[i][j2] = (f32x4)(0.0f);

  auto stage = [&](int ks, int buf) {
    const int tap = ks >> 3;
    const int c0k = (ks & 7) << 5;
    const int kh = tap / 3, kw = tap - kh * 3;
    ushort_t* As_s = &smem[buf][0];
    ushort_t* Bs_s = &smem[buf][8192];
    // A: Wt[b][tap][o 0..255][c0k..+31]; rows lrow and lrow+128
    const ushort_t* ga = wt_b + ((size_t)(tap * 256 + lrow)) * 256 + c0k + cg8;
    gload16(ga, As_s + wave * 512);
    gload16(ga + 128 * 256, As_s + 4096 + wave * 512);
    // B: n = lrow (0..127) -> spatial (h0 + n/64 + kh, n%64 + kw)
    const int sp = (h0 + kh) * 66 + kw + lrow + nrow2;
    gload16(xp_b + (size_t)sp * 256 + c0k + cg8, Bs_s + wave * 512);
  };

  auto compute = [&](int buf) {
    const ushort_t* Ab = &smem[buf][0];
    const ushort_t* Bb = &smem[buf][8192];
    s16x8 bfr[4];
#pragma unroll
    for (int ni = 0; ni < 4; ++ni)
      bfr[ni] = *(const s16x8*)(Bb + boff + ni * 512);
#pragma unroll
    for (int mi = 0; mi < 4; ++mi) {
      s16x8 af = *(const s16x8*)(Ab + aoff + mi * 512);
#pragma unroll
      for (int ni = 0; ni < 4; ++ni)
        acc[mi][ni] = __builtin_amdgcn_mfma_f32_16x16x32_bf16(af, bfr[ni], acc[mi][ni], 0, 0, 0);
    }
  };

  stage(0, 0);
  stage(1, 1);

  int bc = 0;
  for (int ks = 0; ks < 71; ++ks) {
    // wait stage(ks)'s 3 loads; stage(ks+1)'s 3 stay in flight
    asm volatile("s_waitcnt vmcnt(3)" ::: "memory");
    asm volatile("s_barrier" ::: "memory");
    if (ks < 70) {
      int bp = (bc == 0) ? 2 : bc - 1;  // (ks+2) % 3
      stage(ks + 2, bp);
    }
    compute(bc);
    bc = (bc == 2) ? 0 : bc + 1;
  }
  asm volatile("s_waitcnt vmcnt(0)" ::: "memory");
  asm volatile("s_barrier" ::: "memory");
  compute(bc);  // ks = 71

  // Epilogue. C/D layout (m89): col(n) = lane&15, row(m) = (lane>>4)*4 + reg
  float* ob = out + ((size_t)(b * 256 + wm * 64)) * 4096 + ntile * 128 + wn * 64 + lr;
#pragma unroll
  for (int mi = 0; mi < 4; ++mi)
#pragma unroll
    for (int r = 0; r < 4; ++r) {
      float* orow = ob + (size_t)(mi * 16 + lq * 4 + r) * 4096;
#pragma unroll
      for (int ni = 0; ni < 4; ++ni) orow[ni * 16] = acc[mi][ni][r];
    }
}

// ---------------------------------------------------------------------------
extern "C" void kernel_launch(void* const* d_in, const int* in_sizes, int n_in,
                              void* d_out, int out_size, void* d_ws, size_t ws_size,
                              hipStream_t stream) {
  const float* x = (const float*)d_in[0];       // [16,256,64,64]
  const float* thetas = (const float*)d_in[1];  // [16,4]
  const float* scales = (const float*)d_in[2];  // [16,4]
  const float* lambdas = (const float*)d_in[3]; // [16,4]
  const float* weight = (const float*)d_in[4];  // [4,256,256,3,3]
  float* out = (float*)d_out;                   // [16,256,64,64]

  // workspace layout:
  //   barrier u32[16]               @ 0        (zeroed each launch)
  //   Wt   bf16 [16][9][256][256]   @ 4096     (18874368 B)
  //   xpad bf16 [16][66][66][256]   @ 18878464 (35684352 B)
  unsigned int* bar = (unsigned int*)d_ws;
  ushort_t* wt_ws = (ushort_t*)((char*)d_ws + 4096);
  ushort_t* xpad_ws = (ushort_t*)((char*)d_ws + 4096 + 18874368);

  hipMemsetAsync(bar, 0, 64, stream);
  mega_kernel<<<512, 512, 0, stream>>>(x, thetas, scales, lambdas, weight, out,
                                       bar, wt_ws, xpad_ws);
}

// Round 5
// 231.765 us; speedup vs baseline: 2.1294x; 2.1294x over previous
//
#include <hip/hip_runtime.h>
#include <cstdint>
#include <cstddef>

typedef unsigned short ushort_t;
typedef __attribute__((ext_vector_type(4))) float f32x4;
typedef __attribute__((ext_vector_type(8))) short s16x8;

#define PI_4F 0.78539816339744830962f

// round-to-nearest-even fp32 -> bf16
__device__ inline ushort_t f2bf(float f) {
  unsigned int u = __float_as_uint(f);
  u = u + 0x7fffu + ((u >> 16) & 1u);
  return (ushort_t)(u >> 16);
}

// ---------------------------------------------------------------------------
// Kernel 0: rot matrices -> global fp32. 64 threads, one per (b, n) pair.
// ---------------------------------------------------------------------------
__global__ void rot_kernel(const float* __restrict__ thetas, const float* __restrict__ scales,
                           const float* __restrict__ lambdas, float* __restrict__ rot) {
  int tid = threadIdx.x;  // 0..63 == b*4 + n
  float t = thetas[tid], s = scales[tid], lam = lambdas[tid];
  float xv = cosf(t) * s, yv = sinf(t) * s;
  bool pos = (t >= 0.0f), big = (s >= 1.0f), m1 = (fabsf(t) <= PI_4F);
  float M[81];
#pragma unroll
  for (int i = 0; i < 81; ++i) M[i] = 0.0f;
  M[36 + 4] = 1.0f;
  if (pos) {
    float a = xv - yv, bb = xv * yv, c = xv + yv;
    if (m1 && big) {  // pb1
      M[0] = a; M[1] = 1 - a;
      M[9 + 1] = 1 - yv; M[9 + 2] = yv;
      M[18 + 2] = a; M[18 + 5] = 1 - a;
      M[27 + 0] = yv; M[27 + 3] = 1 - yv;
      M[45 + 5] = 1 - yv; M[45 + 8] = yv;
      M[54 + 3] = 1 - a; M[54 + 6] = a;
      M[63 + 6] = yv; M[63 + 7] = 1 - yv;
      M[72 + 7] = 1 - a; M[72 + 8] = a;
    } else if (m1) {  // ps1
      float d = a * c, e = a + c;
      M[0] = d; M[1] = a - d; M[3] = c - d; M[4] = 1 - e + d;
      M[9 + 1] = xv - bb; M[9 + 2] = bb; M[9 + 4] = 1 - c + bb; M[9 + 5] = yv - bb;
      M[18 + 1] = c - d; M[18 + 2] = d; M[18 + 4] = 1 - e + d; M[18 + 5] = a - d;
      M[27 + 0] = bb; M[27 + 1] = yv - bb; M[27 + 3] = xv - bb; M[27 + 4] = 1 - c + bb;
      M[45 + 4] = 1 - c + bb; M[45 + 5] = xv - bb; M[45 + 7] = yv - bb; M[45 + 8] = bb;
      M[54 + 3] = a - d; M[54 + 4] = 1 - e + d; M[54 + 6] = d; M[54 + 7] = c - d;
      M[63 + 3] = yv - bb; M[63 + 4] = 1 - c + bb; M[63 + 6] = bb; M[63 + 7] = xv - bb;
      M[72 + 4] = 1 - e + d; M[72 + 5] = c - d; M[72 + 7] = a - d; M[72 + 8] = d;
    } else {  // pb2 == ps2
      M[0] = a; M[1] = 1 - a;
      M[9 + 1] = xv - bb; M[9 + 2] = bb; M[9 + 4] = 1 - c + bb; M[9 + 5] = yv - bb;
      M[18 + 2] = a; M[18 + 5] = 1 - a;
      M[27 + 0] = bb; M[27 + 1] = yv - bb; M[27 + 3] = xv - bb; M[27 + 4] = 1 - c + bb;
      M[45 + 4] = 1 - c + bb; M[45 + 5] = xv - bb; M[45 + 7] = yv - bb; M[45 + 8] = bb;
      M[54 + 3] = 1 - a; M[54 + 6] = a;
      M[63 + 3] = yv - bb; M[63 + 4] = 1 - c + bb; M[63 + 6] = bb; M[63 + 7] = xv - bb;
      M[72 + 7] = 1 - a; M[72 + 8] = a;
    }
  } else {
    float yp = -yv;
    float ap = xv - yp, bp = xv * yp, cp = xv + yp;
    if (m1 && big) {  // nb1
      M[0] = cp; M[3] = 1 - cp;
      M[9 + 0] = yp; M[9 + 1] = 1 - yp;
      M[18 + 1] = 1 - cp; M[18 + 2] = cp;
      M[27 + 3] = 1 - yp; M[27 + 6] = yp;
      M[45 + 2] = yp; M[45 + 5] = 1 - yp;
      M[54 + 6] = cp; M[54 + 7] = 1 - cp;
      M[63 + 7] = 1 - yp; M[63 + 8] = yp;
      M[72 + 5] = 1 - cp; M[72 + 8] = cp;
    } else if (m1) {  // ns1
      float dp = ap * cp, ep = ap + cp;
      M[0] = dp; M[1] = cp - dp; M[3] = ap - dp; M[4] = 1 - ep + dp;
      M[9 + 0] = bp; M[9 + 1] = xv - bp; M[9 + 3] = yp - bp; M[9 + 4] = 1 - cp + bp;
      M[18 + 1] = ap - dp; M[18 + 2] = dp; M[18 + 4] = 1 - ep + dp; M[18 + 5] = cp - dp;
      M[27 + 1] = yp - bp; M[27 + 2] = bp; M[27 + 4] = 1 - cp + bp; M[27 + 5] = xv - bp;
      M[45 + 3] = xv - bp; M[45 + 4] = 1 - cp + bp; M[45 + 6] = bp; M[45 + 7] = yp - bp;
      M[54 + 3] = cp - dp; M[54 + 4] = 1 - ep + dp; M[54 + 6] = dp; M[54 + 7] = ap - dp;
      M[63 + 4] = 1 - cp + bp; M[63 + 5] = yp - bp; M[63 + 7] = xv - bp; M[63 + 8] = bp;
      M[72 + 4] = 1 - ep + dp; M[72 + 5] = ap - dp; M[72 + 7] = cp - dp; M[72 + 8] = dp;
    } else {  // nb2 == ns2
      M[0] = cp; M[3] = 1 - cp;
      M[9 + 0] = bp; M[9 + 1] = xv - bp; M[9 + 3] = yp - bp; M[9 + 4] = 1 - cp + bp;
      M[18 + 1] = 1 - cp; M[18 + 2] = cp;
      M[27 + 3] = xv - bp; M[27 + 4] = 1 - cp + bp; M[27 + 6] = bp; M[27 + 7] = yp - bp;
      M[45 + 1] = yp - bp; M[45 + 2] = bp; M[45 + 4] = 1 - cp + bp; M[45 + 5] = xv - bp;
      M[54 + 6] = cp; M[54 + 7] = 1 - cp;
      M[63 + 4] = 1 - cp + bp; M[63 + 5] = yp - bp; M[63 + 7] = xv - bp; M[63 + 8] = bp;
      M[72 + 5] = 1 - cp; M[72 + 8] = cp;
    }
  }
  float* r = rot + tid * 81;
#pragma unroll
  for (int i = 0; i < 81; ++i) r[i] = M[i] * lam;
}

// ---------------------------------------------------------------------------
// Kernel 1: Wt[b][i][o][c] (bf16) = sum_n sum_j rot[b,n,i,j] * weight[n,o,c,j]
// Grid: (256 o, 4 bgroup), 256 threads (c). rot via scalar path (uniform idx).
// ---------------------------------------------------------------------------
__global__ void wt_kernel(const float* __restrict__ weight, const float* __restrict__ rot,
                          ushort_t* __restrict__ wtout) {
  const int o = blockIdx.x, bg = blockIdx.y;
  const int c = threadIdx.x;
  float wv[4][9];
#pragma unroll
  for (int n = 0; n < 4; ++n) {
    const float* wp = weight + (((size_t)(n * 256 + o)) * 256 + c) * 9;
#pragma unroll
    for (int j = 0; j < 9; ++j) wv[n][j] = wp[j];
  }
#pragma unroll
  for (int bl = 0; bl < 4; ++bl) {
    const int b = bg * 4 + bl;
#pragma unroll
    for (int i = 0; i < 9; ++i) {
      float acc = 0.0f;
#pragma unroll
      for (int n = 0; n < 4; ++n) {
        const float* r = rot + (b * 4 + n) * 81 + i * 9;
#pragma unroll
        for (int j = 0; j < 9; ++j) acc = fmaf(r[j], wv[n][j], acc);
      }
      wtout[((size_t)((b * 9 + i) * 256 + o)) * 256 + c] = f2bf(acc);
    }
  }
}

// ---------------------------------------------------------------------------
// Kernel 2a: zero only the xpad border
// ---------------------------------------------------------------------------
__global__ void border_zero(ushort_t* __restrict__ xpad) {
  const int p = blockIdx.x, b = blockIdx.y;
  int h, w;
  if (p < 66) { h = 0; w = p; }
  else if (p < 132) { h = 65; w = p - 66; }
  else if (p < 196) { w = 0; h = p - 131; }
  else { w = 65; h = p - 195; }
  size_t base = ((size_t)(b * 4356 + h * 66 + w)) * 256 + threadIdx.x * 4;
  *(uint2*)(xpad + base) = make_uint2(0u, 0u);
}

// ---------------------------------------------------------------------------
// Kernel 2b: x [b][c][h][w] fp32 -> xpad [b][h+1][w+1][c] bf16
// ---------------------------------------------------------------------------
__global__ void transpose_kernel(const float* __restrict__ x, ushort_t* __restrict__ xpad) {
  __shared__ ushort_t tile[64][65];
  const int b = blockIdx.z, ct = blockIdx.y, st = blockIdx.x;  // st = h row
  const int t = threadIdx.x;
  const int l = t & 63, wv = t >> 6;
  const int c0 = ct * 64;
  const float* xb = x + ((size_t)(b * 256 + c0)) * 4096 + st * 64;
#pragma unroll
  for (int k = 0; k < 16; ++k) {
    int c_l = wv + 4 * k;
    tile[l][c_l] = f2bf(xb[(size_t)c_l * 4096 + l]);
  }
  __syncthreads();
  const int hw_l0 = t >> 4, c4 = (t & 15) * 4;
#pragma unroll
  for (int k = 0; k < 4; ++k) {
    int w = hw_l0 + 16 * k;
    uint2 v = *(const uint2*)&tile[w][c4];
    *(uint2*)&xpad[((size_t)(b * 4356 + (st + 1) * 66 + (w + 1))) * 256 + c0 + c4] = v;
  }
}

// ---------------------------------------------------------------------------
// Kernel 3: implicit-GEMM conv, bf16 MFMA.
// Tile 256 o x 128 hw, BK=32, 72 K-steps, 512 threads (8 waves, 64x64/wave).
// 512 blocks = exactly 2/CU. LDS: SIX statically distinct buffers (3-stage
// pipeline, 72 KB) so SIInsertWaitcnts can disambiguate in-flight
// global_load_lds DMA from ds_read (runtime-indexed slices of one array
// force a conservative vmcnt drain every step -> R3's 3.3K cyc/step stall).
// Raw s_barrier + s_waitcnt vmcnt(3): prefetch stays in flight across the
// barrier; never drains to 0 except the peeled tail.
// ---------------------------------------------------------------------------
__device__ inline void gload16(const ushort_t* g, ushort_t* l) {
  __builtin_amdgcn_global_load_lds(
      (const __attribute__((address_space(1))) unsigned int*)g,
      (__attribute__((address_space(3))) unsigned int*)l, 16, 0, 0);
}

#define WAITB(N)                                                      \
  asm volatile("s_waitcnt vmcnt(" #N ") lgkmcnt(0)\n\ts_barrier" ::: "memory")

__global__ __launch_bounds__(512, 4) void conv_kernel(
    const ushort_t* __restrict__ xpad, const ushort_t* __restrict__ wt,
    float* __restrict__ out) {
  // six statically distinct LDS objects
  __shared__ __align__(16) ushort_t As0[8192], As1[8192], As2[8192];  // 16 KB each
  __shared__ __align__(16) ushort_t Bs0[4096], Bs1[4096], Bs2[4096];  //  8 KB each

  const int id = blockIdx.x;
  const int xcd = id & 7;
  const int jj = id >> 3;               // 0..63 within XCD
  const int b = xcd * 2 + (jj >> 5);    // 2 batches per XCD
  const int ntile = jj & 31;

  const int t = threadIdx.x;
  const int wave = t >> 6, lane = t & 63;
  const int wm = wave & 3, wn = wave >> 2;
  const int lr = lane & 15, lq = lane >> 4;
  const int h0 = ntile * 2;

  const ushort_t* wt_b = wt + (size_t)b * 589824;     // 9*256*256
  const ushort_t* xp_b = xpad + (size_t)b * 1115136;  // 4356*256

  const int lrow = t >> 2;                           // 0..127
  const int cg8 = (((t & 3) ^ ((t >> 3) & 3)) * 8);  // swizzled global 16B chunk
  const int rsw = (lr >> 1) & 3;
  const int aoff = (wm * 64 + lr) * 32 + ((lq ^ rsw) * 8);
  const int boff = (wn * 64 + lr) * 32 + ((lq ^ rsw) * 8);
  const int nrow2 = 2 * (lrow >> 6);  // xpad row-adjust for B n>=64

  f32x4 acc[4][4];
#pragma unroll
  for (int i = 0; i < 4; ++i)
#pragma unroll
    for (int j2 = 0; j2 < 4; ++j2) acc[i][j2] = (f32x4)(0.0f);

  auto stage = [&](int ks, ushort_t* Ad, ushort_t* Bd) {
    const int tap = ks >> 3;
    const int c0k = (ks & 7) << 5;
    const int kh = tap / 3, kw = tap - kh * 3;
    // A: Wt[b][tap][o 0..255][c0k..+31]; rows lrow and lrow+128
    const ushort_t* ga = wt_b + ((size_t)(tap * 256 + lrow)) * 256 + c0k + cg8;
    gload16(ga, Ad + wave * 512);
    gload16(ga + 128 * 256, Ad + 4096 + wave * 512);
    // B: n = lrow (0..127) -> spatial (h0 + n/64 + kh, n%64 + kw)
    const int sp = (h0 + kh) * 66 + kw + lrow + nrow2;
    gload16(xp_b + (size_t)sp * 256 + c0k + cg8, Bd + wave * 512);
  };

  auto compute = [&](const ushort_t* Ab, const ushort_t* Bb) {
    s16x8 bfr[4];
#pragma unroll
    for (int ni = 0; ni < 4; ++ni)
      bfr[ni] = *(const s16x8*)(Bb + boff + ni * 512);
#pragma unroll
    for (int mi = 0; mi < 4; ++mi) {
      s16x8 af = *(const s16x8*)(Ab + aoff + mi * 512);
#pragma unroll
      for (int ni = 0; ni < 4; ++ni)
        acc[mi][ni] = __builtin_amdgcn_mfma_f32_16x16x32_bf16(af, bfr[ni], acc[mi][ni], 0, 0, 0);
    }
  };

  stage(0, As0, Bs0);
  stage(1, As1, Bs1);

  // 23 unrolled triples: compute ks = 0..68, stage through ks = 70.
#pragma unroll 1
  for (int kk = 0; kk < 23; ++kk) {
    const int ks = kk * 3;
    WAITB(3);                      // stage(ks) resident; stage(ks+1) in flight
    stage(ks + 2, As2, Bs2);
    compute(As0, Bs0);
    WAITB(3);
    stage(ks + 3, As0, Bs0);
    compute(As1, Bs1);
    WAITB(3);
    stage(ks + 4, As1, Bs1);
    compute(As2, Bs2);
  }
  // tail: outstanding = stage69 (As0), stage70 (As1)
  WAITB(3);                        // stage69 resident
  stage(71, As2, Bs2);
  compute(As0, Bs0);               // ks = 69
  WAITB(3);                        // stage70 resident (71's 3 in flight)
  compute(As1, Bs1);               // ks = 70
  WAITB(0);                        // full drain
  compute(As2, Bs2);               // ks = 71

  // Epilogue. C/D layout (m89): col(n) = lane&15, row(m) = (lane>>4)*4 + reg
  float* ob = out + ((size_t)(b * 256 + wm * 64)) * 4096 + ntile * 128 + wn * 64 + lr;
#pragma unroll
  for (int mi = 0; mi < 4; ++mi)
#pragma unroll
    for (int r = 0; r < 4; ++r) {
      float* orow = ob + (size_t)(mi * 16 + lq * 4 + r) * 4096;
#pragma unroll
      for (int ni = 0; ni < 4; ++ni) orow[ni * 16] = acc[mi][ni][r];
    }
}

// ---------------------------------------------------------------------------
extern "C" void kernel_launch(void* const* d_in, const int* in_sizes, int n_in,
                              void* d_out, int out_size, void* d_ws, size_t ws_size,
                              hipStream_t stream) {
  const float* x = (const float*)d_in[0];       // [16,256,64,64]
  const float* thetas = (const float*)d_in[1];  // [16,4]
  const float* scales = (const float*)d_in[2];  // [16,4]
  const float* lambdas = (const float*)d_in[3]; // [16,4]
  const float* weight = (const float*)d_in[4];  // [4,256,256,3,3]
  float* out = (float*)d_out;                   // [16,256,64,64]

  // workspace layout:
  //   rot  fp32 [64][81]            @ 0        (padded to 32 KB)
  //   Wt   bf16 [16][9][256][256]   @ 32768    (18874368 B)
  //   xpad bf16 [16][66][66][256]   @ 18907136 (35684352 B)
  float* rot_ws = (float*)d_ws;
  ushort_t* wt_ws = (ushort_t*)((char*)d_ws + 32768);
  ushort_t* xpad_ws = (ushort_t*)((char*)d_ws + 32768 + 18874368);

  rot_kernel<<<1, 64, 0, stream>>>(thetas, scales, lambdas, rot_ws);
  wt_kernel<<<dim3(256, 4), 256, 0, stream>>>(weight, rot_ws, wt_ws);
  border_zero<<<dim3(260, 16), 64, 0, stream>>>(xpad_ws);
  transpose_kernel<<<dim3(64, 4, 16), 256, 0, stream>>>(x, xpad_ws);
  conv_kernel<<<512, 512, 0, stream>>>(xpad_ws, wt_ws, out);
}